// Round 8
// baseline (335.004 us; speedup 1.0000x reference)
//
#include <hip/hip_runtime.h>

// MultiHeadAttention: B=4, H=16, N=2048, D=64, C=1024. fp32 I/O, bf16 MFMA compute.
// GEMMs: transposed acc (C^T), BK=64 XOR-swizzled global_load_lds staging.
// Flash: 32x32x16 MFMA; S^T C-layout -> PV B-layout via ONE shfl_xor(32) u64
// exchange per 16-key chunk (no P LDS, no fence). K/V double-buffered
// global_load_lds. q pre-scaled by log2(e)/8 so P = exp2(S) (bare v_exp_f32).

typedef unsigned short u16;
typedef unsigned long long u64;
typedef __bf16 bf16x8 __attribute__((ext_vector_type(8)));
typedef float f32x4 __attribute__((ext_vector_type(4)));
typedef float f32x16 __attribute__((ext_vector_type(16)));

#define MFMA(a, b, c) __builtin_amdgcn_mfma_f32_16x16x32_bf16(a, b, c, 0, 0, 0)
#define MFMA32(a, b, c) __builtin_amdgcn_mfma_f32_32x32x16_bf16(a, b, c, 0, 0, 0)

#define QSCALE 0.18033688011112042f   // log2(e)/8

__device__ __forceinline__ u16 f2bf(float f) {
    __bf16 h = (__bf16)f;          // RNE HW cvt
    return *(u16*)&h;
}

// global -> LDS direct DMA, 16B/lane; l = wave-uniform base, HW adds lane*16.
__device__ __forceinline__ void gld16(const void* g, void* l) {
    __builtin_amdgcn_global_load_lds(
        (const __attribute__((address_space(1))) void*)g,
        (__attribute__((address_space(3))) void*)l, 16, 0, 0);
}

// ---------------------------------------------------------------------------
__global__ __launch_bounds__(256) void cvt_f32_bf16(
    const float* __restrict__ src, u16* __restrict__ dst, long n)
{
    long i = ((long)blockIdx.x * 256 + threadIdx.x) * 8;
    if (i >= n) return;
    float4 a = *(const float4*)&src[i];
    float4 b = *(const float4*)&src[i + 4];
    union { u16 u[8]; uint4 v; } tmp;
    tmp.u[0] = f2bf(a.x); tmp.u[1] = f2bf(a.y);
    tmp.u[2] = f2bf(a.z); tmp.u[3] = f2bf(a.w);
    tmp.u[4] = f2bf(b.x); tmp.u[5] = f2bf(b.y);
    tmp.u[6] = f2bf(b.z); tmp.u[7] = f2bf(b.w);
    *(uint4*)&dst[i] = tmp.v;
}

// ---------------------------------------------------------------------------
__global__ __launch_bounds__(256) void transpose_f2b(
    const float* __restrict__ src, u16* __restrict__ dst, int R, int C)
{
    __shared__ alignas(16) u16 tile[64 * 80];
    const int r0 = blockIdx.y * 64, c0 = blockIdx.x * 64;
    const int t = threadIdx.x;
#pragma unroll
    for (int c = 0; c < 4; c++) {
        int idx = t + c * 256;
        int r = idx >> 4, seg = idx & 15;
        float4 f = *(const float4*)&src[(long)(r0 + r) * C + c0 + seg * 4];
        u16* p = &tile[r * 80 + seg * 4];
        p[0] = f2bf(f.x); p[1] = f2bf(f.y); p[2] = f2bf(f.z); p[3] = f2bf(f.w);
    }
    __syncthreads();
#pragma unroll
    for (int c = 0; c < 2; c++) {
        int idx = t + c * 256;
        int rr = idx >> 3, seg = idx & 7;
        union { u16 u[8]; uint4 v; } tmp;
#pragma unroll
        for (int j = 0; j < 8; j++) tmp.u[j] = tile[(seg * 8 + j) * 80 + rr];
        *(uint4*)&dst[(long)(c0 + rr) * R + r0 + seg * 8] = tmp.v;
    }
}

// ---------------------------------------------------------------------------
// bf16 GEMM, transposed acc (C^T): lane holds 4 consecutive output features.
// 128x128 tile, BK=64, XOR-chunk-swizzled global_load_lds staging.
// EPI 0: packed q(*QSCALE)/k + fused v->vt transpose. EPI 1: float4 fp32 out.
// ---------------------------------------------------------------------------
template <int EPI>
__global__ __launch_bounds__(256) void gemm_bf16(
    const u16* __restrict__ A, const u16* __restrict__ Bt,
    const float* __restrict__ bias,
    u16* __restrict__ out0, u16* __restrict__ out1, u16* __restrict__ out2,
    float* __restrict__ outf,
    int M, int N, int K)
{
    const int m0 = blockIdx.x * 128, n0 = blockIdx.y * 128;
    const int t = threadIdx.x;
    const int wave = t >> 6, lane = t & 63, quad = lane >> 4, l15 = lane & 15;
    const int wm = wave >> 1, wn = wave & 1;

    __shared__ alignas(16) u16 As[128 * 64];
    __shared__ alignas(16) u16 Bs[128 * 64];

    const int srow = wave * 32 + (lane >> 3);
    const int scol = (((lane & 7) ^ (lane >> 3)) & 7) * 8;

    f32x4 acc[4][4] = {};

    for (int k0 = 0; k0 < K; k0 += 64) {
        __syncthreads();
#pragma unroll
        for (int c = 0; c < 4; c++) {
            gld16(&A[(long)(m0 + srow + c * 8) * K + k0 + scol],
                  &As[(wave * 32 + c * 8) * 64]);
            gld16(&Bt[(long)(n0 + srow + c * 8) * K + k0 + scol],
                  &Bs[(wave * 32 + c * 8) * 64]);
        }
        __syncthreads();

#pragma unroll
        for (int ks = 0; ks < 2; ks++) {
            bf16x8 af[4], bf[4];
#pragma unroll
            for (int mt = 0; mt < 4; mt++) {
                int row = wm * 64 + mt * 16 + l15;
                af[mt] = *(bf16x8*)&As[row * 64 + (((ks * 4 + quad) ^ (row & 7)) * 8)];
            }
#pragma unroll
            for (int nt = 0; nt < 4; nt++) {
                int row = wn * 64 + nt * 16 + l15;
                bf[nt] = *(bf16x8*)&Bs[row * 64 + (((ks * 4 + quad) ^ (row & 7)) * 8)];
            }
#pragma unroll
            for (int mt = 0; mt < 4; mt++)
#pragma unroll
                for (int nt = 0; nt < 4; nt++)
                    acc[mt][nt] = MFMA(bf[nt], af[mt], acc[mt][nt]);  // C^T
        }
    }

    // C^T: col=l15 -> token, row=quad*4+r -> output feature
#pragma unroll
    for (int mt = 0; mt < 4; mt++) {
        int token = m0 + wm * 64 + mt * 16 + l15;
        int bb = token >> 11, nn = token & 2047;
#pragma unroll
        for (int nt = 0; nt < 4; nt++) {
            int cgb = n0 + wn * 64 + nt * 16 + quad * 4;
            float4 bv = *(const float4*)&bias[cgb];
            float v0 = acc[mt][nt][0] + bv.x;
            float v1 = acc[mt][nt][1] + bv.y;
            float v2 = acc[mt][nt][2] + bv.z;
            float v3 = acc[mt][nt][3] + bv.w;
            if (EPI == 0) {
                int t3 = cgb >> 10;                 // 0=q 1=k 2=v
                int hh = (cgb >> 6) & 15, dd = cgb & 63;
                int bh = (bb << 4) + hh;
                if (t3 == 0) {
                    union { u16 u[4]; u64 v; } pk;
                    pk.u[0] = f2bf(v0 * QSCALE); pk.u[1] = f2bf(v1 * QSCALE);
                    pk.u[2] = f2bf(v2 * QSCALE); pk.u[3] = f2bf(v3 * QSCALE);
                    *(u64*)&out0[((long)bh * 2048 + nn) * 64 + dd] = pk.v;
                } else if (t3 == 1) {
                    union { u16 u[4]; u64 v; } pk;
                    pk.u[0] = f2bf(v0); pk.u[1] = f2bf(v1);
                    pk.u[2] = f2bf(v2); pk.u[3] = f2bf(v3);
                    *(u64*)&out1[((long)bh * 2048 + nn) * 64 + dd] = pk.v;
                } else {
                    long vbo = ((long)bh * 64 + dd) * 2048 + nn;
                    out2[vbo]            = f2bf(v0);
                    out2[vbo + 2048]     = f2bf(v1);
                    out2[vbo + 2 * 2048] = f2bf(v2);
                    out2[vbo + 3 * 2048] = f2bf(v3);
                }
            } else {
                float4 o4 = { v0, v1, v2, v3 };
                *(float4*)&outf[(long)token * N + cgb] = o4;
            }
        }
    }
}

// ---------------------------------------------------------------------------
// Flash attention v5: 32x32x16 MFMA, no P LDS.
// Grid (N/128, B*H), block 256 = 4 waves, wave owns 32 q-rows (n = lane&31).
// S^T[key][qrow]: C-layout col=lane&31=qrow, row=key=(reg&3)+8*(reg>>2)+4*h1.
// PV B-operand needs keys (16kc + 8*h1 + j) per lane: differs from S^T output
// only by a lane^32 u64 exchange per 16-key chunk kc (derivation in comments).
// K/V tiles double-buffered via global_load_lds with XOR-chunk swizzle;
// fragment reads use chunk ^ (row&7) -> uniform 8 words/bank.
// q pre-scaled by log2(e)/8 -> P = exp2(S). Row-sum via VALU + shfl_xor(32).
// ---------------------------------------------------------------------------
__global__ __launch_bounds__(256, 4) void flash_attn(
    const u16* __restrict__ q, const u16* __restrict__ k,
    const u16* __restrict__ vt, u16* __restrict__ attn)
{
    const int bh = blockIdx.y;
    const int b = bh >> 4, h = bh & 15;
    const int q0 = blockIdx.x * 128;
    const int t = threadIdx.x;
    const int wave = t >> 6, lane = t & 63;
    const int l31 = lane & 31, h1 = lane >> 5;

    __shared__ alignas(16) u16 Ks[2][4096];   // [buf][key*64 + chunk*8]
    __shared__ alignas(16) u16 Vs[2][4096];   // [buf][d*64 + chunk*8]

    const u16* kb = k + (long)bh * 2048 * 64;
    const u16* vb = vt + (long)bh * 64 * 2048;

    // Q as 32x32x16 B-fragment: n=l31 -> qrow, k=h1*8+j -> d (per dc chunk)
    bf16x8 qf[4];
    {
        long row = (long)bh * 2048 + q0 + wave * 32 + l31;
#pragma unroll
        for (int dc = 0; dc < 4; dc++)
            qf[dc] = *(const bf16x8*)&q[row * 64 + dc * 16 + h1 * 8];
    }

    // staging geometry (2 segments/wave; segment = 8 rows x 8 chunks of 16B)
    const int ri = lane >> 3;
    const int ci = (lane & 7) ^ ri;      // XOR-swizzled source chunk
    const int s0 = wave * 2;

    f32x16 o[2] = {};    // O^T acc per 32-d block
    float ls = 0.f;      // row-sum for qrow = l31 (same in both h1 halves)

    // prologue: stage tile 0
#pragma unroll
    for (int c = 0; c < 2; c++) {
        int s = s0 + c;
        gld16(&kb[(long)(s * 8 + ri) * 64 + ci * 8], &Ks[0][s * 512]);
        gld16(&vb[(long)(s * 8 + ri) * 2048 + ci * 8], &Vs[0][s * 512]);
    }

    for (int kt = 0; kt < 32; kt++) {
        const int cur = kt & 1;
        __syncthreads();   // staging(kt) visible; buf(kt-1) reads done

        if (kt < 31) {
#pragma unroll
            for (int c = 0; c < 2; c++) {
                int s = s0 + c;
                gld16(&kb[(long)((kt + 1) * 64 + s * 8 + ri) * 64 + ci * 8],
                      &Ks[cur ^ 1][s * 512]);
                gld16(&vb[(long)(s * 8 + ri) * 2048 + (kt + 1) * 64 + ci * 8],
                      &Vs[cur ^ 1][s * 512]);
            }
        }

        // S^T = K @ Q : A = K-frag (m=key), B = Q-frag; accumulate over d
        f32x16 s2[2];
        s2[0] = (f32x16)0.0f;
        s2[1] = (f32x16)0.0f;
#pragma unroll
        for (int kblk = 0; kblk < 2; kblk++) {
            int row = kblk * 32 + l31;
            const u16* kr = &Ks[cur][row * 64];
            int rm = row & 7;
#pragma unroll
            for (int dc = 0; dc < 4; dc++) {
                bf16x8 kf = *(const bf16x8*)&kr[(((2 * dc + h1) ^ rm) * 8)];
                s2[kblk] = MFMA32(kf, qf[dc], s2[kblk]);
            }
        }

        // P = exp2(S^T); pack per 4-key group: U[kblk*4+rb] = keys
        // kblk*32 + 8*rb + 4*h1 + (0..3) for qrow l31. VALU partial row-sum.
        u64 U[8];
        float part = 0.f;
#pragma unroll
        for (int kblk = 0; kblk < 2; kblk++)
#pragma unroll
            for (int rb = 0; rb < 4; rb++) {
                union { u16 u[4]; u64 v; } pk;
#pragma unroll
                for (int rr = 0; rr < 4; rr++) {
                    float e = exp2f(s2[kblk][rb * 4 + rr]);
                    part += e;
                    pk.u[rr] = f2bf(e);
                }
                U[kblk * 4 + rb] = pk.v;
            }
        ls += part + __shfl_xor(part, 32);   // other 32 keys live in lane^32

        // Per chunk kc: PV B-frag needs keys 16kc+8*h1+(0..7).
        //   low u64 (j=0..3): U[2(kc&1)+h1] of the h1=0 lane
        //   high u64 (j=4..7): U[2(kc&1)+h1] of the h1=1 lane
        // -> each lane sends U[base + (h1^1)], receives partner's via lane^32.
#pragma unroll
        for (int kc = 0; kc < 4; kc++) {
            int base = (kc >> 1) * 4 + (kc & 1) * 2;
            u64 send = U[base + (h1 ^ 1)];
            u64 recv = __shfl_xor(send, 32);
            union { u64 d[2]; bf16x8 v; } pf;
            pf.d[0] = h1 ? recv : U[base];
            pf.d[1] = h1 ? U[base + 1] : recv;
#pragma unroll
            for (int dblk = 0; dblk < 2; dblk++) {
                int row = dblk * 32 + l31;
                const u16* vr = &Vs[cur][row * 64];
                bf16x8 vf = *(const bf16x8*)&vr[(((2 * kc + h1) ^ (row & 7)) * 8)];
                o[dblk] = MFMA32(vf, pf.v, o[dblk]);   // O^T[d][qrow]
            }
        }
    }

    // O^T: col=l31 -> qrow; row = rr + 8*rb + 4*h1 -> d. Packed u64 stores.
    float inv = 1.f / ls;
    int n = q0 + wave * 32 + l31;
#pragma unroll
    for (int dblk = 0; dblk < 2; dblk++)
#pragma unroll
        for (int rb = 0; rb < 4; rb++) {
            union { u16 u[4]; u64 v; } pk;
#pragma unroll
            for (int rr = 0; rr < 4; rr++)
                pk.u[rr] = f2bf(o[dblk][rb * 4 + rr] * inv);
            *(u64*)&attn[((long)b * 2048 + n) * 1024 + h * 64 +
                         dblk * 32 + rb * 8 + h1 * 4] = pk.v;
        }
}

// ---------------------------------------------------------------------------
extern "C" void kernel_launch(void* const* d_in, const int* in_sizes, int n_in,
                              void* d_out, int out_size, void* d_ws, size_t ws_size,
                              hipStream_t stream) {
    const float* x     = (const float*)d_in[0];  // [4,2048,1024]
    const float* w_qkv = (const float*)d_in[1];  // [1024,3072]
    const float* b_qkv = (const float*)d_in[2];  // [3072]
    const float* w_out = (const float*)d_in[3];  // [1024,1024]
    const float* b_out = (const float*)d_in[4];  // [1024]
    float* out = (float*)d_out;                  // [4,2048,1024]

    u16* ws    = (u16*)d_ws;
    u16* q     = ws;                   // [64][2048][64] (BH,N,D), pre-scaled
    u16* kk    = q + 8388608;          // [64][2048][64]
    u16* vt    = kk + 8388608;         // [64][64][2048] (BH,D,N), from GEMM1
    u16* attn  = vt + 8388608;         // [8192][1024]
    u16* x_bf  = attn + 8388608;       // [8192][1024]
    u16* wqkvT = x_bf + 8388608;       // [3072][1024]
    u16* woutT = wqkvT + 3145728;      // [1024][1024]

    cvt_f32_bf16<<<4096, 256, 0, stream>>>(x, x_bf, 8388608L);
    transpose_f2b<<<dim3(48, 16), 256, 0, stream>>>(w_qkv, wqkvT, 1024, 3072);
    transpose_f2b<<<dim3(16, 16), 256, 0, stream>>>(w_out, woutT, 1024, 1024);
    gemm_bf16<0><<<dim3(64, 24), 256, 0, stream>>>(x_bf, wqkvT, b_qkv, q, kk, vt,
                                                   nullptr, 8192, 3072, 1024);
    flash_attn<<<dim3(16, 64), 256, 0, stream>>>(q, kk, vt, attn);
    gemm_bf16<1><<<dim3(64, 8), 256, 0, stream>>>(attn, woutT, b_out, nullptr,
                                                  nullptr, nullptr, out,
                                                  8192, 1024, 1024);
}